// Round 1
// baseline (832.854 us; speedup 1.0000x reference)
//
#include <hip/hip_runtime.h>

#define BB 32
#define NHH 32
#define NKVV 8
#define HDD 128
#define SWW 4096
#define DD 4096
#define GG 4
#define QKVC 6144
#define NSPLIT 8
#define CHUNK (SWW/NSPLIT)  // 512

// ---------------- small-M GEMM: out[32 x ncols] = x[32 x K] @ w[K x ncols] ----
__global__ __launch_bounds__(256) void smallm_gemm(
    const float* __restrict__ x, const float* __restrict__ w,
    float* __restrict__ out, int K, int ncols) {
  __shared__ float xs[BB][64];
  __shared__ float red[4][16][BB + 1];
  const int t = threadIdx.x;
  const int colBase = blockIdx.x * 16;
  const int colOff = t & 15;
  const int ks = t >> 4;  // 0..15 K-slices
  float acc[BB];
#pragma unroll
  for (int r = 0; r < BB; ++r) acc[r] = 0.f;
  for (int kk = 0; kk < K; kk += 64) {
    __syncthreads();
    for (int i = t; i < BB * 64; i += 256) {
      int r = i >> 6, c = i & 63;
      xs[r][c] = x[r * K + kk + c];
    }
    __syncthreads();
#pragma unroll
    for (int k4 = 0; k4 < 4; ++k4) {
      int kloc = ks * 4 + k4;
      float wv = w[(long)(kk + kloc) * ncols + colBase + colOff];
#pragma unroll
      for (int r = 0; r < BB; ++r) acc[r] += xs[r][kloc] * wv;
    }
  }
  // intra-wave reduce across the 4 K-slice groups present in each wave
#pragma unroll
  for (int r = 0; r < BB; ++r) {
    acc[r] += __shfl_xor(acc[r], 16);
    acc[r] += __shfl_xor(acc[r], 32);
  }
  const int lane = t & 63, wvi = t >> 6;
  if ((lane >> 4) == 0) {
#pragma unroll
    for (int r = 0; r < BB; ++r) red[wvi][lane][r] = acc[r];
  }
  __syncthreads();
  for (int i = t; i < 16 * BB; i += 256) {
    int col = i & 15, r = i >> 4;
    out[(long)r * ncols + colBase + col] =
        (red[0][col][r] + red[1][col][r]) + (red[2][col][r] + red[3][col][r]);
  }
}

// ---------------- rotary: row @ rot_mat for all q and k heads ---------------
__global__ __launch_bounds__(128) void rotary_kernel(
    const float* __restrict__ xqkv, const float* __restrict__ rot,
    float* __restrict__ q_rot, float* __restrict__ k_rot) {
  __shared__ float vec[HDD];
  const int blk = blockIdx.x;
  const int j = threadIdx.x;
  const float* src;
  float* dst;
  if (blk < BB * NHH) {
    int b = blk >> 5, h = blk & 31;
    src = xqkv + b * QKVC + h * HDD;
    dst = q_rot + (b * NHH + h) * HDD;
  } else {
    int i = blk - BB * NHH;
    int b = i >> 3, kv = i & 7;
    src = xqkv + b * QKVC + NHH * HDD + kv * HDD;
    dst = k_rot + (b * NKVV + kv) * HDD;
  }
  vec[j] = src[j];
  __syncthreads();
  float a0 = 0.f, a1 = 0.f, a2 = 0.f, a3 = 0.f;
#pragma unroll
  for (int d0 = 0; d0 < HDD; d0 += 4) {
    a0 += vec[d0 + 0] * rot[(d0 + 0) * HDD + j];
    a1 += vec[d0 + 1] * rot[(d0 + 1) * HDD + j];
    a2 += vec[d0 + 2] * rot[(d0 + 2) * HDD + j];
    a3 += vec[d0 + 3] * rot[(d0 + 3) * HDD + j];
  }
  dst[j] = (a0 + a1) + (a2 + a3);
}

// ---------------- flash-decode attention partial (one KV split) -------------
__global__ __launch_bounds__(256) void attn_partial(
    const float* __restrict__ q_rot, const float* __restrict__ k_rot,
    const float* __restrict__ xqkv, const float* __restrict__ cache_k,
    const float* __restrict__ cache_v, const float* __restrict__ mask,
    const int* __restrict__ curpos, float* __restrict__ pm,
    float* __restrict__ pl, float* __restrict__ pacc) {
  __shared__ float sc[GG][CHUNK];  // scores -> probs, 8KB
  const int blk = blockIdx.x;
  const int split = blk & (NSPLIT - 1);
  const int bkv = blk >> 3;
  const int b = bkv >> 3, kv = bkv & 7;
  const int cur = curpos[0];
  const int s0 = split * CHUNK;
  const int t = threadIdx.x, lane = t & 63, wva = t >> 6;
  const int lg = lane & 15;  // 16 lanes cooperate on one key (8 dims each)
  const float scale = 0.08838834764831845f;  // 1/sqrt(128)

  float4 qa[GG], qb[GG];
#pragma unroll
  for (int g = 0; g < GG; ++g) {
    const float* qp = q_rot + ((b * NHH + kv * GG + g) * HDD) + lg * 8;
    qa[g] = *(const float4*)qp;
    qb[g] = *(const float4*)(qp + 4);
  }
  const float* kbase = cache_k + ((long)(b * NKVV + kv)) * SWW * HDD;
  const float* knew = k_rot + (b * NKVV + kv) * HDD;

  // ---- scores: each wave does 4 keys/iter (16 lanes per key) ----
  for (int it = 0; it < CHUNK / 16; ++it) {
    int sloc = it * 16 + wva * 4 + (lane >> 4);
    int s = s0 + sloc;
    const float* kp = (s == cur) ? knew : (kbase + (long)s * HDD);
    float4 ka = *(const float4*)(kp + lg * 8);
    float4 kb = *(const float4*)(kp + lg * 8 + 4);
    float dots[GG];
#pragma unroll
    for (int g = 0; g < GG; ++g) {
      dots[g] = ka.x * qa[g].x + ka.y * qa[g].y + ka.z * qa[g].z +
                ka.w * qa[g].w + kb.x * qb[g].x + kb.y * qb[g].y +
                kb.z * qb[g].z + kb.w * qb[g].w;
    }
#pragma unroll
    for (int m = 1; m < 16; m <<= 1) {
#pragma unroll
      for (int g = 0; g < GG; ++g) dots[g] += __shfl_xor(dots[g], m);
    }
    if (lg == 0) {
#pragma unroll
      for (int g = 0; g < GG; ++g)
        sc[g][sloc] =
            dots[g] * scale + mask[((long)(kv * GG + g) * BB + b) * SWW + s];
    }
  }
  __syncthreads();

  // ---- softmax partial: wave g owns row g ----
  const int g = wva;
  float mx = -1e30f;
  for (int i = lane; i < CHUNK; i += 64) mx = fmaxf(mx, sc[g][i]);
#pragma unroll
  for (int m = 1; m < 64; m <<= 1) mx = fmaxf(mx, __shfl_xor(mx, m));
  float sum = 0.f;
  for (int i = lane; i < CHUNK; i += 64) {
    float e = __expf(sc[g][i] - mx);
    sc[g][i] = e;
    sum += e;
  }
#pragma unroll
  for (int m = 1; m < 64; m <<= 1) sum += __shfl_xor(sum, m);
  const int pidx = (bkv * GG + g) * NSPLIT + split;  // == (b*NH+h)*NSPLIT+split
  if (lane == 0) {
    pm[pidx] = mx;
    pl[pidx] = sum;
  }

  // ---- PV: wave g, lane owns dims (2*lane, 2*lane+1) ----
  const float* vbase = cache_v + ((long)(b * NKVV + kv)) * SWW * HDD;
  const float* vnew = xqkv + b * QKVC + NHH * HDD + NKVV * HDD + kv * HDD;
  const int d = lane * 2;
  float a0 = 0.f, a1 = 0.f;
#pragma unroll 8
  for (int sl = 0; sl < CHUNK; ++sl) {
    int s = s0 + sl;
    const float* vp = (s == cur) ? vnew : (vbase + (long)s * HDD);
    float2 vv = *(const float2*)(vp + d);
    float p = sc[g][sl];
    a0 += p * vv.x;
    a1 += p * vv.y;
  }
  float* pa = pacc + (long)pidx * HDD;
  pa[d] = a0;
  pa[d + 1] = a1;
}

// ---------------- combine split partials -> ctx -----------------------------
__global__ __launch_bounds__(128) void attn_combine(
    const float* __restrict__ pm, const float* __restrict__ pl,
    const float* __restrict__ pacc, float* __restrict__ ctx) {
  const int bh = blockIdx.x;  // b*NH + h
  const int d = threadIdx.x;
  float M = -1e30f;
#pragma unroll
  for (int i = 0; i < NSPLIT; ++i) M = fmaxf(M, pm[bh * NSPLIT + i]);
  float L = 0.f, a = 0.f;
#pragma unroll
  for (int i = 0; i < NSPLIT; ++i) {
    float wexp = __expf(pm[bh * NSPLIT + i] - M);
    L += pl[bh * NSPLIT + i] * wexp;
    a += wexp * pacc[(long)(bh * NSPLIT + i) * HDD + d];
  }
  ctx[bh * HDD + d] = a / L;
}

extern "C" void kernel_launch(void* const* d_in, const int* in_sizes, int n_in,
                              void* d_out, int out_size, void* d_ws,
                              size_t ws_size, hipStream_t stream) {
  const float* x = (const float*)d_in[0];
  const float* wqkv = (const float*)d_in[1];
  const float* wo = (const float*)d_in[2];
  const float* rot = (const float*)d_in[3];
  const float* cache_k = (const float*)d_in[4];
  const float* cache_v = (const float*)d_in[5];
  const float* mask = (const float*)d_in[6];
  const int* curpos = (const int*)d_in[7];
  float* out = (float*)d_out;

  float* ws = (float*)d_ws;
  float* xqkv = ws;                // 32*6144           = 196608
  float* q_rot = xqkv + 196608;    // 32*32*128         = 131072
  float* k_rot = q_rot + 131072;   // 32*8*128          = 32768
  float* pm = k_rot + 32768;       // 32*32*8           = 8192
  float* pl = pm + 8192;           // 8192
  float* pacc = pl + 8192;         // 8192*128          = 1048576
  float* ctx = pacc + 1048576;     // 131072
  (void)in_sizes; (void)n_in; (void)out_size; (void)ws_size;

  hipLaunchKernelGGL(smallm_gemm, dim3(QKVC / 16), dim3(256), 0, stream, x,
                     wqkv, xqkv, DD, QKVC);
  hipLaunchKernelGGL(rotary_kernel, dim3(BB * NHH + BB * NKVV), dim3(128), 0,
                     stream, xqkv, rot, q_rot, k_rot);
  hipLaunchKernelGGL(attn_partial, dim3(BB * NKVV * NSPLIT), dim3(256), 0,
                     stream, q_rot, k_rot, xqkv, cache_k, cache_v, mask, curpos,
                     pm, pl, pacc);
  hipLaunchKernelGGL(attn_combine, dim3(BB * NHH), dim3(128), 0, stream, pm, pl,
                     pacc, ctx);
  hipLaunchKernelGGL(smallm_gemm, dim3(DD / 16), dim3(256), 0, stream, ctx, wo,
                     out, DD, DD);
}

// Round 2
// 341.587 us; speedup vs baseline: 2.4382x; 2.4382x over previous
//
#include <hip/hip_runtime.h>

#define BB 32
#define NHH 32
#define NKVV 8
#define HDD 128
#define SWW 4096
#define DD 4096
#define GG 4
#define QKVC 6144
#define NSPLIT 16
#define CHUNK (SWW / NSPLIT)  // 256
#define KSPB 16

// ============ split-K skinny GEMM partial: part[ky][32][ncols] ==============
// grid (ncols/128, KSPB), block 256 = 64 col-threads (2 cols each) x 4 kgroups
__global__ __launch_bounds__(256) void skinny_gemm_part(
    const float* __restrict__ x, const float* __restrict__ w,
    float* __restrict__ part, int K, int ncols) {
  __shared__ float2 red[4][64][8];
  const int t = threadIdx.x;
  const int ct = t & 63, kg = t >> 6;
  const long c0 = (long)blockIdx.x * 128 + ct * 2;
  const int Kb = K / KSPB;    // 256
  const int klen = Kb / 4;    // 64
  const int k0 = blockIdx.y * Kb + kg * klen;
  float2 acc[BB];
#pragma unroll
  for (int r = 0; r < BB; ++r) acc[r] = make_float2(0.f, 0.f);

  for (int k = k0; k < k0 + klen; k += 4) {
    float2 wv0 = *(const float2*)&w[(long)(k + 0) * ncols + c0];
    float2 wv1 = *(const float2*)&w[(long)(k + 1) * ncols + c0];
    float2 wv2 = *(const float2*)&w[(long)(k + 2) * ncols + c0];
    float2 wv3 = *(const float2*)&w[(long)(k + 3) * ncols + c0];
#pragma unroll
    for (int r = 0; r < BB; ++r) {
      float4 xv = *(const float4*)&x[r * K + k];
      acc[r].x = fmaf(xv.x, wv0.x, acc[r].x);
      acc[r].y = fmaf(xv.x, wv0.y, acc[r].y);
      acc[r].x = fmaf(xv.y, wv1.x, acc[r].x);
      acc[r].y = fmaf(xv.y, wv1.y, acc[r].y);
      acc[r].x = fmaf(xv.z, wv2.x, acc[r].x);
      acc[r].y = fmaf(xv.z, wv2.y, acc[r].y);
      acc[r].x = fmaf(xv.w, wv3.x, acc[r].x);
      acc[r].y = fmaf(xv.w, wv3.y, acc[r].y);
    }
  }
  // in-block reduce over 4 kgroups, 8 rows per round
  for (int rc = 0; rc < 4; ++rc) {
    if (rc) __syncthreads();
#pragma unroll
    for (int j = 0; j < 8; ++j) red[kg][ct][j] = acc[rc * 8 + j];
    __syncthreads();
    if (kg == 0) {
#pragma unroll
      for (int j = 0; j < 8; ++j) {
        float2 s0 = red[0][ct][j], s1 = red[1][ct][j];
        float2 s2 = red[2][ct][j], s3 = red[3][ct][j];
        float2 sm = make_float2((s0.x + s1.x) + (s2.x + s3.x),
                                (s0.y + s1.y) + (s2.y + s3.y));
        *(float2*)&part[((long)blockIdx.y * BB + rc * 8 + j) * ncols + c0] = sm;
      }
    }
  }
}

// ============ reduce split-K partials =======================================
__global__ __launch_bounds__(256) void reduce_part(
    const float* __restrict__ part, float* __restrict__ out, long n) {
  long i = (long)blockIdx.x * 256 + threadIdx.x;
  if (i >= n) return;
  float s = 0.f;
#pragma unroll
  for (int j = 0; j < KSPB; ++j) s += part[(long)j * n + i];
  out[i] = s;
}

// ============ rotary: row @ rot_mat for all q and k heads ===================
__global__ __launch_bounds__(128) void rotary_kernel(
    const float* __restrict__ xqkv, const float* __restrict__ rot,
    float* __restrict__ q_rot, float* __restrict__ k_rot) {
  __shared__ float vec[HDD];
  const int blk = blockIdx.x;
  const int j = threadIdx.x;
  const float* src;
  float* dst;
  if (blk < BB * NHH) {
    int b = blk >> 5, h = blk & 31;
    src = xqkv + (long)b * QKVC + h * HDD;
    dst = q_rot + (long)(b * NHH + h) * HDD;
  } else {
    int i = blk - BB * NHH;
    int b = i >> 3, kv = i & 7;
    src = xqkv + (long)b * QKVC + NHH * HDD + kv * HDD;
    dst = k_rot + (long)(b * NKVV + kv) * HDD;
  }
  vec[j] = src[j];
  __syncthreads();
  float a0 = 0.f, a1 = 0.f, a2 = 0.f, a3 = 0.f;
#pragma unroll
  for (int d0 = 0; d0 < HDD; d0 += 4) {
    a0 += vec[d0 + 0] * rot[(d0 + 0) * HDD + j];
    a1 += vec[d0 + 1] * rot[(d0 + 1) * HDD + j];
    a2 += vec[d0 + 2] * rot[(d0 + 2) * HDD + j];
    a3 += vec[d0 + 3] * rot[(d0 + 3) * HDD + j];
  }
  dst[j] = (a0 + a1) + (a2 + a3);
}

// ============ flash-decode attention partial (one KV split) =================
__global__ __launch_bounds__(256) void attn_partial(
    const float* __restrict__ q_rot, const float* __restrict__ k_rot,
    const float* __restrict__ xqkv, const float* __restrict__ cache_k,
    const float* __restrict__ cache_v, const float* __restrict__ mask,
    const int* __restrict__ curpos, float* __restrict__ pm,
    float* __restrict__ pl, float* __restrict__ pacc) {
  __shared__ float4 scp[CHUNK];      // scores -> probs, [sl] x 4g
  __shared__ float4 mkp[CHUNK];      // mask preload
  __shared__ float red[4][GG][HDD];  // wave partials / reduce scratch

  const int blk = blockIdx.x;
  const int split = blk & (NSPLIT - 1);
  const int bkv = blk >> 4;
  const int b = bkv >> 3, kv = bkv & 7;
  const int cur = curpos[0];
  const int s0 = split * CHUNK;
  const int t = threadIdx.x, lane = t & 63, w = t >> 6;
  const int lg = lane & 15;
  const float scale = 0.08838834764831845f;  // 1/sqrt(128)

  // mask -> LDS (coalesced per g-row)
  for (int i = t; i < GG * CHUNK; i += 256) {
    int g = i >> 8;  // i / CHUNK
    int sl = i & (CHUNK - 1);
    ((float*)mkp)[sl * 4 + g] =
        mask[((long)(kv * GG + g) * BB + b) * SWW + s0 + sl];
  }

  // Q fragments: lane lg holds dims [lg*4..+3] and [64+lg*4..+3]
  float4 qa[GG], qb[GG];
#pragma unroll
  for (int g = 0; g < GG; ++g) {
    const float4* qp =
        (const float4*)(q_rot + (long)((b * NHH + kv * GG + g) * HDD));
    qa[g] = qp[lg];
    qb[g] = qp[lg + 16];
  }
  const float* kbase = cache_k + (long)(b * NKVV + kv) * SWW * HDD;
  const float* knew = k_rot + (long)(b * NKVV + kv) * HDD;
  __syncthreads();

  // ---- scores: wave handles 4 keys/iter, 16 lanes per key ----
#pragma unroll 2
  for (int it = 0; it < CHUNK / 16; ++it) {
    int sloc = it * 16 + w * 4 + (lane >> 4);
    int s = s0 + sloc;
    const float4* kp =
        (const float4*)((s == cur) ? knew : (kbase + (long)s * HDD));
    float4 ka = kp[lg];
    float4 kb = kp[lg + 16];
    float dots[GG];
#pragma unroll
    for (int g = 0; g < GG; ++g) {
      dots[g] = ka.x * qa[g].x + ka.y * qa[g].y + ka.z * qa[g].z +
                ka.w * qa[g].w + kb.x * qb[g].x + kb.y * qb[g].y +
                kb.z * qb[g].z + kb.w * qb[g].w;
    }
#pragma unroll
    for (int m = 1; m < 16; m <<= 1) {
#pragma unroll
      for (int g = 0; g < GG; ++g) dots[g] += __shfl_xor(dots[g], m);
    }
    if (lg == 0) {
      float4 mv = mkp[sloc];
      float4 sv;
      sv.x = fmaf(dots[0], scale, mv.x);
      sv.y = fmaf(dots[1], scale, mv.y);
      sv.z = fmaf(dots[2], scale, mv.z);
      sv.w = fmaf(dots[3], scale, mv.w);
      scp[sloc] = sv;
    }
  }
  __syncthreads();

  // ---- softmax partial: wave w owns sl in [w*64, w*64+64) ----
  const int sl = w * 64 + lane;
  float4 e = scp[sl];
  float4 mx = e;
#pragma unroll
  for (int m = 1; m < 64; m <<= 1) {
    mx.x = fmaxf(mx.x, __shfl_xor(mx.x, m));
    mx.y = fmaxf(mx.y, __shfl_xor(mx.y, m));
    mx.z = fmaxf(mx.z, __shfl_xor(mx.z, m));
    mx.w = fmaxf(mx.w, __shfl_xor(mx.w, m));
  }
  if (lane == 0) *(float4*)&red[w][0][0] = mx;
  __syncthreads();
  float4 m0 = *(const float4*)&red[0][0][0];
  float4 m1 = *(const float4*)&red[1][0][0];
  float4 m2 = *(const float4*)&red[2][0][0];
  float4 m3 = *(const float4*)&red[3][0][0];
  float4 Mx;
  Mx.x = fmaxf(fmaxf(m0.x, m1.x), fmaxf(m2.x, m3.x));
  Mx.y = fmaxf(fmaxf(m0.y, m1.y), fmaxf(m2.y, m3.y));
  Mx.z = fmaxf(fmaxf(m0.z, m1.z), fmaxf(m2.z, m3.z));
  Mx.w = fmaxf(fmaxf(m0.w, m1.w), fmaxf(m2.w, m3.w));
  float4 p;
  p.x = __expf(e.x - Mx.x);
  p.y = __expf(e.y - Mx.y);
  p.z = __expf(e.z - Mx.z);
  p.w = __expf(e.w - Mx.w);
  scp[sl] = p;
  float4 sm = p;
#pragma unroll
  for (int m = 1; m < 64; m <<= 1) {
    sm.x += __shfl_xor(sm.x, m);
    sm.y += __shfl_xor(sm.y, m);
    sm.z += __shfl_xor(sm.z, m);
    sm.w += __shfl_xor(sm.w, m);
  }
  if (lane == 0) *(float4*)&red[w][1][0] = sm;
  __syncthreads();
  float4 t0 = *(const float4*)&red[0][1][0];
  float4 t1 = *(const float4*)&red[1][1][0];
  float4 t2 = *(const float4*)&red[2][1][0];
  float4 t3 = *(const float4*)&red[3][1][0];
  if (t == 0) {
    long base = ((long)(b * NHH + kv * GG)) * NSPLIT + split;
    pm[base + 0 * NSPLIT] = Mx.x;
    pm[base + 1 * NSPLIT] = Mx.y;
    pm[base + 2 * NSPLIT] = Mx.z;
    pm[base + 3 * NSPLIT] = Mx.w;
    pl[base + 0 * NSPLIT] = (t0.x + t1.x) + (t2.x + t3.x);
    pl[base + 1 * NSPLIT] = (t0.y + t1.y) + (t2.y + t3.y);
    pl[base + 2 * NSPLIT] = (t0.z + t1.z) + (t2.z + t3.z);
    pl[base + 3 * NSPLIT] = (t0.w + t1.w) + (t2.w + t3.w);
  }
  __syncthreads();  // protect red reuse below

  // ---- PV: wave w covers its own sl range; lane owns float4 of dims ----
  const float* vbase = cache_v + (long)(b * NKVV + kv) * SWW * HDD;
  const float* vnew =
      xqkv + (long)b * QKVC + NHH * HDD + NKVV * HDD + kv * HDD;
  const int dl = lane & 31;
  const int half = lane >> 5;
  float4 acc0 = make_float4(0, 0, 0, 0), acc1 = acc0, acc2 = acc0,
         acc3 = acc0;
#pragma unroll 4
  for (int it = 0; it < 32; ++it) {
    int slp = w * 64 + it * 2 + half;
    float4 v4 = *(const float4*)(vbase + (long)(s0 + slp) * HDD + dl * 4);
    float4 p4 = scp[slp];
    acc0.x = fmaf(p4.x, v4.x, acc0.x);
    acc0.y = fmaf(p4.x, v4.y, acc0.y);
    acc0.z = fmaf(p4.x, v4.z, acc0.z);
    acc0.w = fmaf(p4.x, v4.w, acc0.w);
    acc1.x = fmaf(p4.y, v4.x, acc1.x);
    acc1.y = fmaf(p4.y, v4.y, acc1.y);
    acc1.z = fmaf(p4.y, v4.z, acc1.z);
    acc1.w = fmaf(p4.y, v4.w, acc1.w);
    acc2.x = fmaf(p4.z, v4.x, acc2.x);
    acc2.y = fmaf(p4.z, v4.y, acc2.y);
    acc2.z = fmaf(p4.z, v4.z, acc2.z);
    acc2.w = fmaf(p4.z, v4.w, acc2.w);
    acc3.x = fmaf(p4.w, v4.x, acc3.x);
    acc3.y = fmaf(p4.w, v4.y, acc3.y);
    acc3.z = fmaf(p4.w, v4.z, acc3.z);
    acc3.w = fmaf(p4.w, v4.w, acc3.w);
  }
  // fixup: the split containing cur must use the NEW v row, not the cache
  if (cur >= s0 && cur < s0 + CHUNK) {
    int slc = cur - s0;
    if (w == (slc >> 6) && half == (slc & 1)) {
      float4 p4 = scp[slc];
      float4 vc = *(const float4*)(vbase + (long)cur * HDD + dl * 4);
      float4 vn = *(const float4*)(vnew + dl * 4);
      float4 d;
      d.x = vn.x - vc.x;
      d.y = vn.y - vc.y;
      d.z = vn.z - vc.z;
      d.w = vn.w - vc.w;
      acc0.x = fmaf(p4.x, d.x, acc0.x);
      acc0.y = fmaf(p4.x, d.y, acc0.y);
      acc0.z = fmaf(p4.x, d.z, acc0.z);
      acc0.w = fmaf(p4.x, d.w, acc0.w);
      acc1.x = fmaf(p4.y, d.x, acc1.x);
      acc1.y = fmaf(p4.y, d.y, acc1.y);
      acc1.z = fmaf(p4.y, d.z, acc1.z);
      acc1.w = fmaf(p4.y, d.w, acc1.w);
      acc2.x = fmaf(p4.z, d.x, acc2.x);
      acc2.y = fmaf(p4.z, d.y, acc2.y);
      acc2.z = fmaf(p4.z, d.z, acc2.z);
      acc2.w = fmaf(p4.z, d.w, acc2.w);
      acc3.x = fmaf(p4.w, d.x, acc3.x);
      acc3.y = fmaf(p4.w, d.y, acc3.y);
      acc3.z = fmaf(p4.w, d.z, acc3.z);
      acc3.w = fmaf(p4.w, d.w, acc3.w);
    }
  }
  // combine the two s-parity halves
  acc0.x += __shfl_xor(acc0.x, 32);
  acc0.y += __shfl_xor(acc0.y, 32);
  acc0.z += __shfl_xor(acc0.z, 32);
  acc0.w += __shfl_xor(acc0.w, 32);
  acc1.x += __shfl_xor(acc1.x, 32);
  acc1.y += __shfl_xor(acc1.y, 32);
  acc1.z += __shfl_xor(acc1.z, 32);
  acc1.w += __shfl_xor(acc1.w, 32);
  acc2.x += __shfl_xor(acc2.x, 32);
  acc2.y += __shfl_xor(acc2.y, 32);
  acc2.z += __shfl_xor(acc2.z, 32);
  acc2.w += __shfl_xor(acc2.w, 32);
  acc3.x += __shfl_xor(acc3.x, 32);
  acc3.y += __shfl_xor(acc3.y, 32);
  acc3.z += __shfl_xor(acc3.z, 32);
  acc3.w += __shfl_xor(acc3.w, 32);
  if (half == 0) {
    *(float4*)&red[w][0][dl * 4] = acc0;
    *(float4*)&red[w][1][dl * 4] = acc1;
    *(float4*)&red[w][2][dl * 4] = acc2;
    *(float4*)&red[w][3][dl * 4] = acc3;
  }
  __syncthreads();
  if (t < HDD) {
#pragma unroll
    for (int g = 0; g < GG; ++g) {
      float s = (red[0][g][t] + red[1][g][t]) + (red[2][g][t] + red[3][g][t]);
      pacc[(((long)(b * NHH + kv * GG + g)) * NSPLIT + split) * HDD + t] = s;
    }
  }
}

// ============ combine split partials -> ctx =================================
__global__ __launch_bounds__(128) void attn_combine(
    const float* __restrict__ pm, const float* __restrict__ pl,
    const float* __restrict__ pacc, float* __restrict__ ctx) {
  const int bh = blockIdx.x;
  const int d = threadIdx.x;
  float M = -1e30f;
#pragma unroll
  for (int i = 0; i < NSPLIT; ++i) M = fmaxf(M, pm[bh * NSPLIT + i]);
  float L = 0.f, a = 0.f;
#pragma unroll
  for (int i = 0; i < NSPLIT; ++i) {
    float wexp = __expf(pm[bh * NSPLIT + i] - M);
    L += pl[bh * NSPLIT + i] * wexp;
    a += wexp * pacc[((long)bh * NSPLIT + i) * HDD + d];
  }
  ctx[(long)bh * HDD + d] = a / L;
}

extern "C" void kernel_launch(void* const* d_in, const int* in_sizes, int n_in,
                              void* d_out, int out_size, void* d_ws,
                              size_t ws_size, hipStream_t stream) {
  const float* x = (const float*)d_in[0];
  const float* wqkv = (const float*)d_in[1];
  const float* wo = (const float*)d_in[2];
  const float* rot = (const float*)d_in[3];
  const float* cache_k = (const float*)d_in[4];
  const float* cache_v = (const float*)d_in[5];
  const float* mask = (const float*)d_in[6];
  const int* curpos = (const int*)d_in[7];
  float* out = (float*)d_out;

  float* ws = (float*)d_ws;
  float* xqkv = ws;               // 196608
  float* q_rot = xqkv + 196608;   // 131072
  float* k_rot = q_rot + 131072;  // 32768
  float* pm = k_rot + 32768;      // 16384
  float* pl = pm + 16384;         // 16384
  float* ctx = pl + 16384;        // 131072
  float* big = ctx + 131072;      // 3145728 (gemm partials / pacc, time-shared)
  (void)in_sizes; (void)n_in; (void)out_size; (void)ws_size;

  // QKV projection (split-K) + reduce
  hipLaunchKernelGGL(skinny_gemm_part, dim3(QKVC / 128, KSPB), dim3(256), 0,
                     stream, x, wqkv, big, DD, QKVC);
  hipLaunchKernelGGL(reduce_part, dim3((BB * QKVC) / 256), dim3(256), 0,
                     stream, big, xqkv, (long)BB * QKVC);
  // rotary for q and k heads
  hipLaunchKernelGGL(rotary_kernel, dim3(BB * NHH + BB * NKVV), dim3(128), 0,
                     stream, xqkv, rot, q_rot, k_rot);
  // flash-decode attention
  hipLaunchKernelGGL(attn_partial, dim3(BB * NKVV * NSPLIT), dim3(256), 0,
                     stream, q_rot, k_rot, xqkv, cache_k, cache_v, mask,
                     curpos, pm, pl, big);
  hipLaunchKernelGGL(attn_combine, dim3(BB * NHH), dim3(128), 0, stream, pm,
                     pl, big, ctx);
  // output projection (split-K) + reduce
  hipLaunchKernelGGL(skinny_gemm_part, dim3(DD / 128, KSPB), dim3(256), 0,
                     stream, ctx, wo, big, DD, DD);
  hipLaunchKernelGGL(reduce_part, dim3((BB * DD) / 256), dim3(256), 0, stream,
                     big, out, (long)BB * DD);
}